// Round 2
// baseline (431.155 us; speedup 1.0000x reference)
//
#include <hip/hip_runtime.h>
#include <cstdint>
#include <cstddef>

typedef int i32x4  __attribute__((ext_vector_type(4)));
typedef int i32x16 __attribute__((ext_vector_type(16)));

#define BM 256
#define BN 256
#define BK 64   // bytes of K per tile = 2 k-steps of 32 for mfma_i32_32x32x32_i8

__device__ __forceinline__ void load16_to_lds(const void* g, void* l) {
  __builtin_amdgcn_global_load_lds(
      (const __attribute__((address_space(1))) void*)g,
      (__attribute__((address_space(3))) void*)l,
      16, 0, 0);
}

// Fused input quantization.
// Blocks [0, M): per-row absmax + int8 quantize of x (row held in regs).
// Blocks [M, M + N*K/4096): pack int32 weights (values in [-127,127]) to int8.
__global__ __launch_bounds__(256) void quant_xw(const float* __restrict__ x,
                                                char* __restrict__ xq,
                                                float* __restrict__ sx,
                                                const int* __restrict__ w,
                                                char* __restrict__ wq,
                                                int M, int K) {
  const int t = threadIdx.x;
  __shared__ float red[4];
  if ((int)blockIdx.x < M) {
    const int row = blockIdx.x;
    const float* xr = x + (size_t)row * K;
    float4 v[4];
    float amax = 0.f;
#pragma unroll
    for (int j = 0; j < 4; ++j) {
      v[j] = ((const float4*)xr)[t + j * 256];
      amax = fmaxf(amax, fmaxf(fmaxf(fabsf(v[j].x), fabsf(v[j].y)),
                               fmaxf(fabsf(v[j].z), fabsf(v[j].w))));
    }
#pragma unroll
    for (int off = 32; off; off >>= 1)
      amax = fmaxf(amax, __shfl_xor(amax, off));
    if ((t & 63) == 0) red[t >> 6] = amax;
    __syncthreads();
    amax = fmaxf(fmaxf(red[0], red[1]), fmaxf(red[2], red[3]));
    amax = fmaxf(amax, 1e-20f);

    const float s = 127.0f / amax;
    int* outw = (int*)(xq + (size_t)row * K);
#pragma unroll
    for (int j = 0; j < 4; ++j) {
      int q0 = __float2int_rn(v[j].x * s);
      int q1 = __float2int_rn(v[j].y * s);
      int q2 = __float2int_rn(v[j].z * s);
      int q3 = __float2int_rn(v[j].w * s);
      int pk = (q0 & 0xff) | ((q1 & 0xff) << 8) | ((q2 & 0xff) << 16) | ((q3 & 0xff) << 24);
      outw[t + j * 256] = pk;
    }
    if (t == 0) sx[row] = amax * (1.0f / 127.0f);
  } else {
    const size_t base = (size_t)(blockIdx.x - M) * 4096;
    int* outw = (int*)(wq + base);
#pragma unroll
    for (int j = 0; j < 4; ++j) {
      const int c = t + j * 256;
      int4 a = ((const int4*)(w + base))[c];
      outw[c] = (a.x & 0xff) | ((a.y & 0xff) << 8) | ((a.z & 0xff) << 16) | ((a.w & 0xff) << 24);
    }
  }
}

// C[m][n] = sum_k A[m][k]*Bw[n][k] (int8 -> int32); out = C*sx[m]*sw[n] + bias[n].
// 256x256 tile, 512 thr (8 waves: 2M x 4N), BK=64B.
// mfma_i32_32x32x32_i8: per wave 4x2 tiles of 32x32, 8 MFMA per k-step, 2 k-steps/tile.
// Schedule per tile (3-buffer rotation, counted vmcnt, setprio around MFMA):
//   phase A: 6 ds_reads(ks0) + stage A-half(t+2) | bar | lgkm0 | issue 6 ds_reads(ks1)
//            overlapping the 8 MFMA(ks0) | bar
//   phase B: stage B-half(t+2) | bar | lgkm0 | 8 MFMA(ks1) | vmcnt(4) | bar
// LDS swizzle: 16B chunk (row r, k-chunk c in 0..3) at byte r*64 + ((c ^ ((r>>1)&3))<<4);
// staged via pre-swizzled global source so global_load_lds dst stays linear (chunk q -> q*16).
__global__ __launch_bounds__(512) void gemm_i8_bt(const char* __restrict__ A,
                                                  const char* __restrict__ Bw,
                                                  const float* __restrict__ sx,
                                                  const float* __restrict__ sw,
                                                  const float* __restrict__ bias,
                                                  float* __restrict__ out,
                                                  int M, int N, int K) {
  __shared__ __align__(16) char As[3][BM * BK];   // 3 x 16 KiB
  __shared__ __align__(16) char Bs[3][BN * BK];   // 3 x 16 KiB  (96 KiB total)

  const int tid  = threadIdx.x;
  const int wave = tid >> 6;
  const int lane = tid & 63;
  const int wm   = wave >> 2;      // 0..1 -> 128-row half
  const int wn   = wave & 3;       // 0..3 -> 64-col quarter

  // XCD-aware bijective block swizzle (nwg = 512, divisible by 8)
  const int gx   = N / BN;                              // 16
  const int nwg  = gx * (M / BM);                       // 512
  const int orig = blockIdx.y * gx + blockIdx.x;
  const int wg   = (orig & 7) * (nwg >> 3) + (orig >> 3);
  const int bn   = wg % gx;
  const int bm   = wg / gx;

  i32x16 acc[4][2] = {};

  // Staging: thread stages 16B chunks q=tid and q=tid+512 of each tile.
  // LDS chunk position p=q&3 of row q>>2 holds global chunk p ^ ((row>>1)&3).
  const int rowT = tid >> 2;
  const int jg   = ((tid & 3) ^ ((tid >> 3) & 3)) << 4;
  const char* Ag1 = A  + (size_t)(bm * BM + rowT) * K + jg;
  const char* Ag2 = Ag1 + (size_t)128 * K;
  const char* Bg1 = Bw + (size_t)(bn * BN + rowT) * K + jg;
  const char* Bg2 = Bg1 + (size_t)128 * K;

  const int ldsO1 = wave << 10;             // chunk q=tid      -> byte tid*16
  const int ldsO2 = 8192 + (wave << 10);    // chunk q=tid+512

  // Fragment read offsets: lane holds row (lane&31) of the 32-row block, k-chunk lane>>5
  // within k-step s. Global chunk c = s*2 + (lane>>5) sits at byte r*64 + ((c^((r>>1)&3))<<4).
  // ((r>>1)&3) == ((fr>>1)&3): all block offsets (wm*128, m*32, wn*64, n*32) are 0 mod 8.
  const int fr = lane & 31;
  const int jj = lane >> 5;
  const int st = (fr >> 1) & 3;
  int offA[4][2], offB[2][2];
#pragma unroll
  for (int m = 0; m < 4; ++m)
#pragma unroll
    for (int s = 0; s < 2; ++s)
      offA[m][s] = (wm * 128 + m * 32 + fr) * 64 + (((s * 2 + jj) ^ st) << 4);
#pragma unroll
  for (int n = 0; n < 2; ++n)
#pragma unroll
    for (int s = 0; s < 2; ++s)
      offB[n][s] = (wn * 64 + n * 32 + fr) * 64 + (((s * 2 + jj) ^ st) << 4);

  const int NT = K / BK;    // 64

  // Prologue: stage tiles 0,1 into buffers 0,1; wait tile 0 (keep tile 1 in flight).
  load16_to_lds(Ag1,      &As[0][ldsO1]);
  load16_to_lds(Ag2,      &As[0][ldsO2]);
  load16_to_lds(Bg1,      &Bs[0][ldsO1]);
  load16_to_lds(Bg2,      &Bs[0][ldsO2]);
  load16_to_lds(Ag1 + BK, &As[1][ldsO1]);
  load16_to_lds(Ag2 + BK, &As[1][ldsO2]);
  load16_to_lds(Bg1 + BK, &Bs[1][ldsO1]);
  load16_to_lds(Bg2 + BK, &Bs[1][ldsO2]);
  asm volatile("s_waitcnt vmcnt(4)" ::: "memory");
  __builtin_amdgcn_s_barrier();

  int buf = 0;                              // tile t lives in buffer t % 3
  for (int t = 0; t < NT; ++t) {
    const int  nb = (buf >= 1) ? buf - 1 : 2;      // (t+2) % 3
    const size_t ko = (size_t)(t + 2) * BK;
    const bool pf = (t + 2) < NT;

    // ---------- phase A: k-step 0 ----------
    i32x4 a00 = *(const i32x4*)&As[buf][offA[0][0]];
    i32x4 a01 = *(const i32x4*)&As[buf][offA[1][0]];
    i32x4 a02 = *(const i32x4*)&As[buf][offA[2][0]];
    i32x4 a03 = *(const i32x4*)&As[buf][offA[3][0]];
    i32x4 b00 = *(const i32x4*)&Bs[buf][offB[0][0]];
    i32x4 b01 = *(const i32x4*)&Bs[buf][offB[1][0]];
    if (pf) {
      load16_to_lds(Ag1 + ko, &As[nb][ldsO1]);
      load16_to_lds(Ag2 + ko, &As[nb][ldsO2]);
    }
    __builtin_amdgcn_s_barrier();
    asm volatile("s_waitcnt lgkmcnt(0)" ::: "memory");
    __builtin_amdgcn_sched_barrier(0);
    // k-step 1 fragment reads: overlap with the MFMA cluster below; waited in phase B.
    i32x4 a10 = *(const i32x4*)&As[buf][offA[0][1]];
    i32x4 a11 = *(const i32x4*)&As[buf][offA[1][1]];
    i32x4 a12 = *(const i32x4*)&As[buf][offA[2][1]];
    i32x4 a13 = *(const i32x4*)&As[buf][offA[3][1]];
    i32x4 b10 = *(const i32x4*)&Bs[buf][offB[0][1]];
    i32x4 b11 = *(const i32x4*)&Bs[buf][offB[1][1]];
    __builtin_amdgcn_s_setprio(1);
    acc[0][0] = __builtin_amdgcn_mfma_i32_32x32x32_i8(a00, b00, acc[0][0], 0, 0, 0);
    acc[0][1] = __builtin_amdgcn_mfma_i32_32x32x32_i8(a00, b01, acc[0][1], 0, 0, 0);
    acc[1][0] = __builtin_amdgcn_mfma_i32_32x32x32_i8(a01, b00, acc[1][0], 0, 0, 0);
    acc[1][1] = __builtin_amdgcn_mfma_i32_32x32x32_i8(a01, b01, acc[1][1], 0, 0, 0);
    acc[2][0] = __builtin_amdgcn_mfma_i32_32x32x32_i8(a02, b00, acc[2][0], 0, 0, 0);
    acc[2][1] = __builtin_amdgcn_mfma_i32_32x32x32_i8(a02, b01, acc[2][1], 0, 0, 0);
    acc[3][0] = __builtin_amdgcn_mfma_i32_32x32x32_i8(a03, b00, acc[3][0], 0, 0, 0);
    acc[3][1] = __builtin_amdgcn_mfma_i32_32x32x32_i8(a03, b01, acc[3][1], 0, 0, 0);
    __builtin_amdgcn_s_setprio(0);
    __builtin_amdgcn_s_barrier();

    // ---------- phase B: k-step 1 ----------
    if (pf) {
      load16_to_lds(Bg1 + ko, &Bs[nb][ldsO1]);
      load16_to_lds(Bg2 + ko, &Bs[nb][ldsO2]);
    }
    __builtin_amdgcn_s_barrier();
    asm volatile("s_waitcnt lgkmcnt(0)" ::: "memory");
    __builtin_amdgcn_sched_barrier(0);
    __builtin_amdgcn_s_setprio(1);
    acc[0][0] = __builtin_amdgcn_mfma_i32_32x32x32_i8(a10, b10, acc[0][0], 0, 0, 0);
    acc[0][1] = __builtin_amdgcn_mfma_i32_32x32x32_i8(a10, b11, acc[0][1], 0, 0, 0);
    acc[1][0] = __builtin_amdgcn_mfma_i32_32x32x32_i8(a11, b10, acc[1][0], 0, 0, 0);
    acc[1][1] = __builtin_amdgcn_mfma_i32_32x32x32_i8(a11, b11, acc[1][1], 0, 0, 0);
    acc[2][0] = __builtin_amdgcn_mfma_i32_32x32x32_i8(a12, b10, acc[2][0], 0, 0, 0);
    acc[2][1] = __builtin_amdgcn_mfma_i32_32x32x32_i8(a12, b11, acc[2][1], 0, 0, 0);
    acc[3][0] = __builtin_amdgcn_mfma_i32_32x32x32_i8(a13, b10, acc[3][0], 0, 0, 0);
    acc[3][1] = __builtin_amdgcn_mfma_i32_32x32x32_i8(a13, b11, acc[3][1], 0, 0, 0);
    __builtin_amdgcn_s_setprio(0);

    // Tile boundary: retire tile t+1's 4 loads, keep tile t+2's 4 in flight.
    if (pf)                 { asm volatile("s_waitcnt vmcnt(4)" ::: "memory"); }
    else if (t + 1 < NT)    { asm volatile("s_waitcnt vmcnt(0)" ::: "memory"); }
    __builtin_amdgcn_s_barrier();

    buf = (buf < 2) ? buf + 1 : 0;
  }

  // Epilogue. 32x32 C/D layout: col = lane&31, row = (reg&3) + 8*(reg>>2) + 4*(lane>>5).
  const int colc = lane & 31;
  const int rhi  = (lane >> 5) << 2;
  const int col0 = bn * BN + wn * 64 + colc;
  const float sc0 = sw[col0],      bi0 = bias[col0];
  const float sc1 = sw[col0 + 32], bi1 = bias[col0 + 32];
#pragma unroll
  for (int m = 0; m < 4; ++m) {
    const int row0 = bm * BM + wm * 128 + m * 32 + rhi;
#pragma unroll
    for (int r = 0; r < 16; ++r) {
      const int row = row0 + (r & 3) + ((r >> 2) << 3);
      const float srow = sx[row];
      float* op = out + (size_t)row * N + col0;
      op[0]  = (float)acc[m][0][r] * (srow * sc0) + bi0;
      op[32] = (float)acc[m][1][r] * (srow * sc1) + bi1;
    }
  }
}

extern "C" void kernel_launch(void* const* d_in, const int* in_sizes, int n_in,
                              void* d_out, int out_size, void* d_ws, size_t ws_size,
                              hipStream_t stream) {
  const float* x     = (const float*)d_in[0];
  const int*   w     = (const int*)d_in[1];
  const float* scale = (const float*)d_in[2];
  const float* bias  = (const float*)d_in[3];
  float*       out   = (float*)d_out;

  const int N = in_sizes[3];          // D_OUT = 4096
  const int K = in_sizes[1] / N;      // D_IN  = 4096
  const int M = in_sizes[0] / K;      // B*S   = 8192

  char*  xq = (char*)d_ws;                       // M*K i8  = 32 MiB
  char*  wq = xq + (size_t)M * K;                // N*K i8  = 16 MiB
  float* sx = (float*)(wq + (size_t)N * K);      // M floats

  const unsigned wblocks = (unsigned)(((size_t)N * K) / 4096);
  quant_xw<<<dim3((unsigned)M + wblocks), dim3(256), 0, stream>>>(x, xq, sx, w, wq, M, K);

  gemm_i8_bt<<<dim3(N / BN, M / BM), dim3(512), 0, stream>>>(xq, wq, sx, scale, bias, out, M, N, K);
}